// Round 5
// baseline (759.570 us; speedup 1.0000x reference)
//
#include <hip/hip_runtime.h>
#include <hip/hip_bf16.h>

typedef float f32x4 __attribute__((ext_vector_type(4)));
typedef float f32x2 __attribute__((ext_vector_type(2)));
typedef short bf16x8 __attribute__((ext_vector_type(8)));
typedef unsigned int u32;
typedef unsigned int u32x2 __attribute__((ext_vector_type(2)));
typedef unsigned short u16;

#define DEVI static __device__ __forceinline__

static constexpr int HD    = 256;      // hidden
static constexpr int NNODE = 10000;

DEVI u16 f2bf(float f) {
  __hip_bfloat16 h = __float2bfloat16(f);   // RNE; compiler can fuse pairs into v_cvt_pk_bf16_f32
  return __builtin_bit_cast(u16, h);
}
DEVI u32 f2bf2(float a, float b) {          // pack two bf16 into u32 (low = a)
  return (u32)f2bf(a) | ((u32)f2bf(b) << 16);
}
DEVI float bf2f(u16 s) {
  u32 u = ((u32)s) << 16;
  return __builtin_bit_cast(float, u);
}
DEVI float gelu_f(float y) {
  float z = 0.7978845608028654f * (y + 0.044715f * y * y * y);
  float E = __expf(2.f * z);
  return y * (1.f - 1.f / (E + 1.f));
}

// ---------------- weight prep ----------------
// Wlt [256][128] = W_lin^T (bf16); W1gt[256][256] = (g_pre*W_ff1)^T; W2t = W_ff2^T
__global__ void prep_weights(const float* __restrict__ W_lin, const float* __restrict__ g_pre,
                             const float* __restrict__ W_ff1, const float* __restrict__ W_ff2,
                             u16* __restrict__ Wlt, u16* __restrict__ W1gt, u16* __restrict__ W2t)
{
  int e = blockIdx.x * 256 + threadIdx.x;
  if (e < 32768) {
    int c = e >> 7, k = e & 127;
    Wlt[e] = f2bf(W_lin[k * 256 + c]);
  } else if (e < 32768 + 65536) {
    int e2 = e - 32768; int c = e2 >> 8, k = e2 & 255;
    W1gt[e2] = f2bf(g_pre[k] * W_ff1[k * 256 + c]);
  } else if (e < 163840) {
    int e3 = e - 98304; int c = e3 >> 8, k = e3 & 255;
    W2t[e3] = f2bf(W_ff2[k * 256 + c]);
  }
}

__global__ void prep_uv(const float* __restrict__ W_ff1, const float* __restrict__ g_pre,
                        const float* __restrict__ b_pre, const float* __restrict__ b_ff1,
                        float* __restrict__ u, float* __restrict__ v)
{
  int c = threadIdx.x;
  float uu = 0.f, vv = 0.f;
#pragma unroll 8
  for (int k = 0; k < 256; ++k) {
    float w = W_ff1[k * 256 + c];
    uu += g_pre[k] * w;
    vv += b_pre[k] * w;
  }
  u[c] = uu;
  v[c] = vv + b_ff1[c];
}

// ---------------- GEMM inner loop (no barriers) ----------------
// A from swizzled xLDS (STRIDE bytes/row, 16B chunk index ^ (r&7));
// B direct from global W^T (L2-resident), col cc row = NK*64 bytes.
// acc layout: row r = rg*16 + lo; col = wc*64 + nt*16 + hi*4 + j.
template<int NK, int STRIDE>
DEVI void run_gemm(f32x4 (&acc)[4][4], const char* __restrict__ xbase,
                   const u16* __restrict__ Wt, int lo, int hi, int wc)
{
  const char* __restrict__ wp = (const char*)Wt;
#pragma unroll
  for (int ks = 0; ks < NK; ++ks) {
    bf16x8 a[4], b[4];
#pragma unroll
    for (int nt = 0; nt < 4; ++nt) {
      int cc = wc * 64 + nt * 16 + lo;
      b[nt] = *(const bf16x8*)(wp + (size_t)cc * (NK * 64) + ks * 64 + hi * 16);
    }
#pragma unroll
    for (int rg = 0; rg < 4; ++rg) {
      int r = rg * 16 + lo;
      a[rg] = *(const bf16x8*)(xbase + r * STRIDE + (((ks * 4 + hi) ^ (r & 7)) << 4));
    }
#pragma unroll
    for (int nt = 0; nt < 4; ++nt)
#pragma unroll
      for (int rg = 0; rg < 4; ++rg)
        acc[rg][nt] = __builtin_amdgcn_mfma_f32_16x16x32_bf16(b[nt], a[rg], acc[rg][nt], 0, 0, 0);
  }
}

// ---------------- fused megakernel ----------------
// Block = 64 rows = 2 nodes. 256 threads = 4 waves (1 row-group x 4 col-groups).
// xLDS [64][256] bf16 (chunk-swizzled) serves as: A-stage (16KB) -> eh -> g -> eo.
// Residual eh kept packed-bf16 in 32 registers.
__global__ __launch_bounds__(256, 4)
void mega_kernel(const float* __restrict__ EF, const int* __restrict__ nmask,
                 const u16* __restrict__ Wlt, const u16* __restrict__ W1gt, const u16* __restrict__ W2t,
                 const float* __restrict__ b_lin, const float* __restrict__ uc, const float* __restrict__ vc,
                 const float* __restrict__ b_ff2, const float* __restrict__ g_edge, const float* __restrict__ b_edge,
                 const float* __restrict__ g_node, const float* __restrict__ b_node,
                 float* __restrict__ node_out, float* __restrict__ edge_out)
{
  const int tid  = threadIdx.x;
  const int lane = tid & 63;
  const int wc   = tid >> 6;      // wave = column group 0..3
  const int lo   = lane & 15;
  const int hi   = lane >> 4;
  const int tile0 = blockIdx.x * 64;

  __shared__ char  xLDS[32768];
  __shared__ float part[4][64][2];
  __shared__ int   lm[64];
  __shared__ float red[4][2];

  if (tid < 64) lm[tid] = nmask[tile0 + tid];

  // ---- stage A: EF fp32 -> bf16 into xLDS rows of 256B (swizzled 16B chunks) ----
#pragma unroll
  for (int it = 0; it < 4; ++it) {
    int idx = it * 256 + tid;
    int r = idx >> 4, sl = idx & 15;
    const float* src = EF + (size_t)(tile0 + r) * 128 + sl * 8;
    f32x4 x0 = *(const f32x4*)src;
    f32x4 x1 = *(const f32x4*)(src + 4);
    bf16x8 t;
    u32 p0 = f2bf2(x0[0], x0[1]);
    u32 p1 = f2bf2(x0[2], x0[3]);
    u32 p2 = f2bf2(x1[0], x1[1]);
    u32 p3 = f2bf2(x1[2], x1[3]);
    t[0] = (short)(p0 & 0xffffu); t[1] = (short)(p0 >> 16);
    t[2] = (short)(p1 & 0xffffu); t[3] = (short)(p1 >> 16);
    t[4] = (short)(p2 & 0xffffu); t[5] = (short)(p2 >> 16);
    t[6] = (short)(p3 & 0xffffu); t[7] = (short)(p3 >> 16);
    *(bf16x8*)(xLDS + r * 256 + ((sl ^ (r & 7)) << 4)) = t;
  }
  __syncthreads();

  f32x4 acc[4][4];
#pragma unroll
  for (int rg = 0; rg < 4; ++rg)
#pragma unroll
    for (int nt = 0; nt < 4; ++nt) acc[rg][nt] = f32x4{0.f, 0.f, 0.f, 0.f};

  // ---- GEMM1: eh = EF x W_lin (K=128) ----
  run_gemm<4, 256>(acc, xLDS, Wlt, lo, hi, wc);

  // ---- EPI1: +b_lin, keep eh packed in regs, row stats ----
  u32x2 ehreg[4][4];
  {
    f32x4 bl[4];
#pragma unroll
    for (int nt = 0; nt < 4; ++nt)
      bl[nt] = *(const f32x4*)(b_lin + wc * 64 + nt * 16 + hi * 4);
#pragma unroll
    for (int rg = 0; rg < 4; ++rg) {
      int r = rg * 16 + lo;
      float ss = 0.f, qq = 0.f;
#pragma unroll
      for (int nt = 0; nt < 4; ++nt) {
        f32x4 x = acc[rg][nt] + bl[nt];
        ehreg[rg][nt] = u32x2{f2bf2(x[0], x[1]), f2bf2(x[2], x[3])};
        ss += x[0] + x[1] + x[2] + x[3];
        qq += x[0]*x[0] + x[1]*x[1] + x[2]*x[2] + x[3]*x[3];
      }
      ss += __shfl_xor(ss, 16); ss += __shfl_xor(ss, 32);
      qq += __shfl_xor(qq, 16); qq += __shfl_xor(qq, 32);
      if (hi == 0) { part[wc][r][0] = ss; part[wc][r][1] = qq; }
    }
  }
  __syncthreads();            // GEMM1 A-reads done; part complete
  if (tid < 64) {
    float ss = part[0][tid][0] + part[1][tid][0] + part[2][tid][0] + part[3][tid][0];
    float qq = part[0][tid][1] + part[1][tid][1] + part[2][tid][1] + part[3][tid][1];
    float m  = ss * (1.f / 256.f);
    float var = qq * (1.f / 256.f) - m * m;
    part[0][tid][0] = m;
    part[0][tid][1] = rsqrtf(var + 1e-5f);
  }
  // write eh bf16 into xLDS (rows now 512B): slot sl holds cols sl*8..+8, ^ (r&7)
#pragma unroll
  for (int rg = 0; rg < 4; ++rg) {
    int r = rg * 16 + lo;
#pragma unroll
    for (int nt = 0; nt < 4; ++nt) {
      int slot = wc * 8 + nt * 2 + (hi >> 1);
      *(u32x2*)(xLDS + r * 512 + ((slot ^ (r & 7)) << 4) + (hi & 1) * 8) = ehreg[rg][nt];
    }
  }
  __syncthreads();            // eh + stats ready

  // ---- GEMM2: acc = eh x (g_pre*W_ff1) (K=256) ----
#pragma unroll
  for (int rg = 0; rg < 4; ++rg)
#pragma unroll
    for (int nt = 0; nt < 4; ++nt) acc[rg][nt] = f32x4{0.f, 0.f, 0.f, 0.f};
  run_gemm<8, 512>(acc, xLDS, W1gt, lo, hi, wc);
  __syncthreads();            // all eh reads done before overwrite with g

  // ---- EPI2: folded pre-LN + gelu -> g into xLDS ----
  {
    f32x4 u4[4], v4[4];
#pragma unroll
    for (int nt = 0; nt < 4; ++nt) {
      u4[nt] = *(const f32x4*)(uc + wc * 64 + nt * 16 + hi * 4);
      v4[nt] = *(const f32x4*)(vc + wc * 64 + nt * 16 + hi * 4);
    }
#pragma unroll
    for (int rg = 0; rg < 4; ++rg) {
      int r = rg * 16 + lo;
      float m  = part[0][r][0];
      float rs = part[0][r][1];
      float rm = m * rs;
#pragma unroll
      for (int nt = 0; nt < 4; ++nt) {
        f32x4 y = acc[rg][nt] * rs - u4[nt] * rm + v4[nt];
        u32 w0 = f2bf2(gelu_f(y[0]), gelu_f(y[1]));
        u32 w1 = f2bf2(gelu_f(y[2]), gelu_f(y[3]));
        int slot = wc * 8 + nt * 2 + (hi >> 1);
        *(u32x2*)(xLDS + r * 512 + ((slot ^ (r & 7)) << 4) + (hi & 1) * 8) = u32x2{w0, w1};
      }
    }
  }
  __syncthreads();            // g ready

  // ---- GEMM3: acc = g x W_ff2 (K=256) ----
#pragma unroll
  for (int rg = 0; rg < 4; ++rg)
#pragma unroll
    for (int nt = 0; nt < 4; ++nt) acc[rg][nt] = f32x4{0.f, 0.f, 0.f, 0.f};
  run_gemm<8, 512>(acc, xLDS, W2t, lo, hi, wc);

  // ---- EPI3: +b_ff2 + residual(eh regs); edge LN stats ----
  {
    f32x4 b2[4];
#pragma unroll
    for (int nt = 0; nt < 4; ++nt)
      b2[nt] = *(const f32x4*)(b_ff2 + wc * 64 + nt * 16 + hi * 4);
#pragma unroll
    for (int rg = 0; rg < 4; ++rg) {
      int r = rg * 16 + lo;
      float ss = 0.f, qq = 0.f;
#pragma unroll
      for (int nt = 0; nt < 4; ++nt) {
        f32x4 x = acc[rg][nt] + b2[nt];
        x[0] += bf2f((u16)(ehreg[rg][nt][0] & 0xffffu));
        x[1] += bf2f((u16)(ehreg[rg][nt][0] >> 16));
        x[2] += bf2f((u16)(ehreg[rg][nt][1] & 0xffffu));
        x[3] += bf2f((u16)(ehreg[rg][nt][1] >> 16));
        acc[rg][nt] = x;
        ss += x[0] + x[1] + x[2] + x[3];
        qq += x[0]*x[0] + x[1]*x[1] + x[2]*x[2] + x[3]*x[3];
      }
      ss += __shfl_xor(ss, 16); ss += __shfl_xor(ss, 32);
      qq += __shfl_xor(qq, 16); qq += __shfl_xor(qq, 32);
      if (hi == 0) { part[wc][r][0] = ss; part[wc][r][1] = qq; }
    }
  }
  __syncthreads();            // GEMM3 reads done; part complete
  if (tid < 64) {
    float ss = part[0][tid][0] + part[1][tid][0] + part[2][tid][0] + part[3][tid][0];
    float qq = part[0][tid][1] + part[1][tid][1] + part[2][tid][1] + part[3][tid][1];
    float m  = ss * (1.f / 256.f);
    float var = qq * (1.f / 256.f) - m * m;
    part[0][tid][0] = m;
    part[0][tid][1] = rsqrtf(var + 1e-5f);
  }
  __syncthreads();

  // ---- edge_out (LN, fp32) + eo bf16 -> xLDS ----
  {
    f32x4 ge4[4], be4[4];
#pragma unroll
    for (int nt = 0; nt < 4; ++nt) {
      ge4[nt] = *(const f32x4*)(g_edge + wc * 64 + nt * 16 + hi * 4);
      be4[nt] = *(const f32x4*)(b_edge + wc * 64 + nt * 16 + hi * 4);
    }
#pragma unroll
    for (int rg = 0; rg < 4; ++rg) {
      int r = rg * 16 + lo;
      float m2  = part[0][r][0];
      float rs2 = part[0][r][1];
#pragma unroll
      for (int nt = 0; nt < 4; ++nt) {
        f32x4 x = acc[rg][nt];
        u32 w0 = f2bf2(x[0], x[1]);
        u32 w1 = f2bf2(x[2], x[3]);
        int slot = wc * 8 + nt * 2 + (hi >> 1);
        *(u32x2*)(xLDS + r * 512 + ((slot ^ (r & 7)) << 4) + (hi & 1) * 8) = u32x2{w0, w1};
        f32x4 o = (x - m2) * rs2 * ge4[nt] + be4[nt];
        *(f32x4*)(edge_out + (size_t)(tile0 + r) * 256 + wc * 64 + nt * 16 + hi * 4) = o;
      }
    }
  }
  __syncthreads();            // eo ready

  // ---- node aggregation (2 nodes) + node LN ----
  {
    int nd = tid >> 7;                 // node within block (wave-uniform)
    int c0 = (tid & 127) * 2;          // column pair
    int chunk = c0 >> 3;
    int wib = (c0 & 7) * 2;            // byte within 16B chunk
    float s0 = 0.f, s1 = 0.f;
#pragma unroll
    for (int r32 = 0; r32 < 32; ++r32) {
      int r = nd * 32 + r32;
      if (lm[r] != 0) {
        u32 w = *(const u32*)(xLDS + r * 512 + ((chunk ^ (r & 7)) << 4) + wib);
        s0 += bf2f((u16)(w & 0xffffu));
        s1 += bf2f((u16)(w >> 16));
      }
    }
    float ss = s0 + s1, qq = s0 * s0 + s1 * s1;
#pragma unroll
    for (int d = 1; d < 64; d <<= 1) { ss += __shfl_xor(ss, d); qq += __shfl_xor(qq, d); }
    if (lane == 0) { red[wc][0] = ss; red[wc][1] = qq; }
    __syncthreads();
    ss = red[nd * 2][0] + red[nd * 2 + 1][0];
    qq = red[nd * 2][1] + red[nd * 2 + 1][1];
    float m   = ss * (1.f / 256.f);
    float var = qq * (1.f / 256.f) - m * m;
    float rs  = rsqrtf(var + 1e-5f);
    f32x2 gn = *(const f32x2*)(g_node + c0);
    f32x2 bn = *(const f32x2*)(b_node + c0);
    f32x2 o;
    o[0] = (s0 - m) * rs * gn[0] + bn[0];
    o[1] = (s1 - m) * rs * gn[1] + bn[1];
    *(f32x2*)(node_out + (size_t)(blockIdx.x * 2 + nd) * 256 + c0) = o;
  }
}

extern "C" void kernel_launch(void* const* d_in, const int* in_sizes, int n_in,
                              void* d_out, int out_size, void* d_ws, size_t ws_size,
                              hipStream_t stream)
{
  (void)in_sizes; (void)n_in; (void)out_size; (void)ws_size;
  const float* edge_features = (const float*)d_in[0];
  const int*   nmask  = (const int*)d_in[1];
  const float* W_lin  = (const float*)d_in[2];
  const float* b_lin  = (const float*)d_in[3];
  const float* g_pre  = (const float*)d_in[4];
  const float* b_pre  = (const float*)d_in[5];
  const float* W_ff1  = (const float*)d_in[6];
  const float* b_ff1  = (const float*)d_in[7];
  const float* W_ff2  = (const float*)d_in[8];
  const float* b_ff2  = (const float*)d_in[9];
  const float* g_node = (const float*)d_in[10];
  const float* b_node = (const float*)d_in[11];
  const float* g_edge = (const float*)d_in[12];
  const float* b_edge = (const float*)d_in[13];

  char* ws = (char*)d_ws;
  u16* Wlt   = (u16*)ws;   ws += 256 * 128 * 2;
  u16* W1gt  = (u16*)ws;   ws += 256 * 256 * 2;
  u16* W2t   = (u16*)ws;   ws += 256 * 256 * 2;
  float* ucp = (float*)ws; ws += 256 * 4;
  float* vcp = (float*)ws; ws += 256 * 4;

  float* node_out = (float*)d_out;
  float* edge_out = (float*)d_out + (size_t)NNODE * HD;

  prep_weights<<<640, 256, 0, stream>>>(W_lin, g_pre, W_ff1, W_ff2, Wlt, W1gt, W2t);
  prep_uv<<<1, 256, 0, stream>>>(W_ff1, g_pre, b_pre, b_ff1, ucp, vcp);
  mega_kernel<<<5000, 256, 0, stream>>>(edge_features, nmask, Wlt, W1gt, W2t,
                                        b_lin, ucp, vcp, b_ff2, g_edge, b_edge,
                                        g_node, b_node, node_out, edge_out);
}

// Round 6
// 729.318 us; speedup vs baseline: 1.0415x; 1.0415x over previous
//
#include <hip/hip_runtime.h>
#include <hip/hip_bf16.h>

typedef float f32x4 __attribute__((ext_vector_type(4)));
typedef float f32x2 __attribute__((ext_vector_type(2)));
typedef short bf16x8 __attribute__((ext_vector_type(8)));
typedef unsigned int u32;
typedef unsigned int u32x2 __attribute__((ext_vector_type(2)));
typedef unsigned short u16;

#define DEVI static __device__ __forceinline__

static constexpr int HD    = 256;      // hidden
static constexpr int NNODE = 10000;

DEVI u16 f2bf(float f) {
  __hip_bfloat16 h = __float2bfloat16(f);   // RNE; pairs fuse into v_cvt_pk_bf16_f32
  return __builtin_bit_cast(u16, h);
}
DEVI u32 f2bf2(float a, float b) {          // pack two bf16 into u32 (low = a)
  return (u32)f2bf(a) | ((u32)f2bf(b) << 16);
}
DEVI float bf2f(u16 s) {
  u32 u = ((u32)s) << 16;
  return __builtin_bit_cast(float, u);
}
DEVI float gelu_f(float y) {
  float z = 0.7978845608028654f * (y + 0.044715f * y * y * y);
  float E = __expf(2.f * z);
  return y * (1.f - 1.f / (E + 1.f));
}

// ---------------- weight prep ----------------
// Wlt [256][128] = W_lin^T (bf16); W1gt[256][256] = (g_pre*W_ff1)^T; W2t = W_ff2^T
__global__ void prep_weights(const float* __restrict__ W_lin, const float* __restrict__ g_pre,
                             const float* __restrict__ W_ff1, const float* __restrict__ W_ff2,
                             u16* __restrict__ Wlt, u16* __restrict__ W1gt, u16* __restrict__ W2t)
{
  int e = blockIdx.x * 256 + threadIdx.x;
  if (e < 32768) {
    int c = e >> 7, k = e & 127;
    Wlt[e] = f2bf(W_lin[k * 256 + c]);
  } else if (e < 32768 + 65536) {
    int e2 = e - 32768; int c = e2 >> 8, k = e2 & 255;
    W1gt[e2] = f2bf(g_pre[k] * W_ff1[k * 256 + c]);
  } else if (e < 163840) {
    int e3 = e - 98304; int c = e3 >> 8, k = e3 & 255;
    W2t[e3] = f2bf(W_ff2[k * 256 + c]);
  }
}

// 256 blocks x 64 lanes: block c computes u[c], v[c]
__global__ void prep_uv(const float* __restrict__ W_ff1, const float* __restrict__ g_pre,
                        const float* __restrict__ b_pre, const float* __restrict__ b_ff1,
                        float* __restrict__ u, float* __restrict__ v)
{
  int c = blockIdx.x;
  int lane = threadIdx.x;
  float uu = 0.f, vv = 0.f;
#pragma unroll
  for (int i = 0; i < 4; ++i) {
    int k = lane + i * 64;
    float w = W_ff1[k * 256 + c];
    uu += g_pre[k] * w;
    vv += b_pre[k] * w;
  }
#pragma unroll
  for (int d = 1; d < 64; d <<= 1) { uu += __shfl_xor(uu, d); vv += __shfl_xor(vv, d); }
  if (lane == 0) {
    u[c] = uu;
    v[c] = vv + b_ff1[c];
  }
}

// ---------------- GEMM inner loop (no barriers, 1-step B prefetch) ----------------
// A from swizzled xLDS (STRIDE bytes/row, 16B chunk index ^ (r&7));
// B direct from global W^T (L2-resident); per-nt base pointer + imm offset ks*64.
// acc layout: row r = rg*16 + lo; col = wc*64 + nt*16 + hi*4 + j.
template<int NK, int STRIDE>
DEVI void run_gemm(f32x4 (&acc)[4][4], const char* __restrict__ xbase,
                   const u16* __restrict__ Wt, int lo, int hi, int wc)
{
  const char* bp[4];
#pragma unroll
  for (int nt = 0; nt < 4; ++nt) {
    int cc = wc * 64 + nt * 16 + lo;
    bp[nt] = (const char*)Wt + (size_t)cc * (NK * 64) + hi * 16;
  }
  bf16x8 bcur[4];
#pragma unroll
  for (int nt = 0; nt < 4; ++nt) bcur[nt] = *(const bf16x8*)(bp[nt]);
#pragma unroll
  for (int ks = 0; ks < NK; ++ks) {
    bf16x8 bnxt[4];
    if (ks + 1 < NK) {
#pragma unroll
      for (int nt = 0; nt < 4; ++nt) bnxt[nt] = *(const bf16x8*)(bp[nt] + (ks + 1) * 64);
    }
    bf16x8 a[4];
#pragma unroll
    for (int rg = 0; rg < 4; ++rg) {
      int r = rg * 16 + lo;
      a[rg] = *(const bf16x8*)(xbase + r * STRIDE + (((ks * 4 + hi) ^ (r & 7)) << 4));
    }
#pragma unroll
    for (int nt = 0; nt < 4; ++nt)
#pragma unroll
      for (int rg = 0; rg < 4; ++rg)
        acc[rg][nt] = __builtin_amdgcn_mfma_f32_16x16x32_bf16(bcur[nt], a[rg], acc[rg][nt], 0, 0, 0);
    if (ks + 1 < NK) {
#pragma unroll
      for (int nt = 0; nt < 4; ++nt) bcur[nt] = bnxt[nt];
    }
  }
}

// ---------------- fused megakernel ----------------
// Block = 64 rows = 2 nodes. 256 threads = 4 waves (1 row-group x 4 col-groups).
// xLDS [64][256] bf16 (chunk-swizzled) serves as: A-stage (16KB) -> eh -> g -> eo.
// Residual eh kept packed-bf16 in 32 registers.
__global__ __launch_bounds__(256, 3)
void mega_kernel(const float* __restrict__ EF, const int* __restrict__ nmask,
                 const u16* __restrict__ Wlt, const u16* __restrict__ W1gt, const u16* __restrict__ W2t,
                 const float* __restrict__ b_lin, const float* __restrict__ uc, const float* __restrict__ vc,
                 const float* __restrict__ b_ff2, const float* __restrict__ g_edge, const float* __restrict__ b_edge,
                 const float* __restrict__ g_node, const float* __restrict__ b_node,
                 float* __restrict__ node_out, float* __restrict__ edge_out)
{
  const int tid  = threadIdx.x;
  const int lane = tid & 63;
  const int wc   = tid >> 6;      // wave = column group 0..3
  const int lo   = lane & 15;
  const int hi   = lane >> 4;
  const int tile0 = blockIdx.x * 64;

  __shared__ char  xLDS[32768];
  __shared__ float part[4][64][2];
  __shared__ int   lm[64];
  __shared__ float red[4][2];

  if (tid < 64) lm[tid] = nmask[tile0 + tid];

  // ---- stage A: EF fp32 -> bf16 into xLDS rows of 256B (swizzled 16B chunks) ----
#pragma unroll
  for (int it = 0; it < 4; ++it) {
    int idx = it * 256 + tid;
    int r = idx >> 4, sl = idx & 15;
    const float* src = EF + (size_t)(tile0 + r) * 128 + sl * 8;
    f32x4 x0 = *(const f32x4*)src;
    f32x4 x1 = *(const f32x4*)(src + 4);
    bf16x8 t;
    u32 p0 = f2bf2(x0[0], x0[1]);
    u32 p1 = f2bf2(x0[2], x0[3]);
    u32 p2 = f2bf2(x1[0], x1[1]);
    u32 p3 = f2bf2(x1[2], x1[3]);
    t[0] = (short)(p0 & 0xffffu); t[1] = (short)(p0 >> 16);
    t[2] = (short)(p1 & 0xffffu); t[3] = (short)(p1 >> 16);
    t[4] = (short)(p2 & 0xffffu); t[5] = (short)(p2 >> 16);
    t[6] = (short)(p3 & 0xffffu); t[7] = (short)(p3 >> 16);
    *(bf16x8*)(xLDS + r * 256 + ((sl ^ (r & 7)) << 4)) = t;
  }
  __syncthreads();

  f32x4 acc[4][4];
#pragma unroll
  for (int rg = 0; rg < 4; ++rg)
#pragma unroll
    for (int nt = 0; nt < 4; ++nt) acc[rg][nt] = f32x4{0.f, 0.f, 0.f, 0.f};

  // ---- GEMM1: eh = EF x W_lin (K=128) ----
  run_gemm<4, 256>(acc, xLDS, Wlt, lo, hi, wc);

  // ---- EPI1: +b_lin, keep eh packed in regs, row stats ----
  u32x2 ehreg[4][4];
  {
    f32x4 bl[4];
#pragma unroll
    for (int nt = 0; nt < 4; ++nt)
      bl[nt] = *(const f32x4*)(b_lin + wc * 64 + nt * 16 + hi * 4);
#pragma unroll
    for (int rg = 0; rg < 4; ++rg) {
      int r = rg * 16 + lo;
      float ss = 0.f, qq = 0.f;
#pragma unroll
      for (int nt = 0; nt < 4; ++nt) {
        f32x4 x = acc[rg][nt] + bl[nt];
        ehreg[rg][nt] = u32x2{f2bf2(x[0], x[1]), f2bf2(x[2], x[3])};
        ss += x[0] + x[1] + x[2] + x[3];
        qq += x[0]*x[0] + x[1]*x[1] + x[2]*x[2] + x[3]*x[3];
      }
      ss += __shfl_xor(ss, 16); ss += __shfl_xor(ss, 32);
      qq += __shfl_xor(qq, 16); qq += __shfl_xor(qq, 32);
      if (hi == 0) { part[wc][r][0] = ss; part[wc][r][1] = qq; }
    }
  }
  __syncthreads();            // GEMM1 A-reads done; part complete
  if (tid < 64) {
    float ss = part[0][tid][0] + part[1][tid][0] + part[2][tid][0] + part[3][tid][0];
    float qq = part[0][tid][1] + part[1][tid][1] + part[2][tid][1] + part[3][tid][1];
    float m  = ss * (1.f / 256.f);
    float var = qq * (1.f / 256.f) - m * m;
    part[0][tid][0] = m;
    part[0][tid][1] = rsqrtf(var + 1e-5f);
  }
  // write eh bf16 into xLDS (rows now 512B): slot sl holds cols sl*8..+8, ^ (r&7)
#pragma unroll
  for (int rg = 0; rg < 4; ++rg) {
    int r = rg * 16 + lo;
#pragma unroll
    for (int nt = 0; nt < 4; ++nt) {
      int slot = wc * 8 + nt * 2 + (hi >> 1);
      *(u32x2*)(xLDS + r * 512 + ((slot ^ (r & 7)) << 4) + (hi & 1) * 8) = ehreg[rg][nt];
    }
  }
  __syncthreads();            // eh + stats ready

  // ---- GEMM2: acc = eh x (g_pre*W_ff1) (K=256) ----
#pragma unroll
  for (int rg = 0; rg < 4; ++rg)
#pragma unroll
    for (int nt = 0; nt < 4; ++nt) acc[rg][nt] = f32x4{0.f, 0.f, 0.f, 0.f};
  run_gemm<8, 512>(acc, xLDS, W1gt, lo, hi, wc);
  __syncthreads();            // all eh reads done before overwrite with g

  // ---- EPI2: folded pre-LN + gelu -> g into xLDS ----
  {
    f32x4 u4[4], v4[4];
#pragma unroll
    for (int nt = 0; nt < 4; ++nt) {
      u4[nt] = *(const f32x4*)(uc + wc * 64 + nt * 16 + hi * 4);
      v4[nt] = *(const f32x4*)(vc + wc * 64 + nt * 16 + hi * 4);
    }
#pragma unroll
    for (int rg = 0; rg < 4; ++rg) {
      int r = rg * 16 + lo;
      float m  = part[0][r][0];
      float rs = part[0][r][1];
      float rm = m * rs;
#pragma unroll
      for (int nt = 0; nt < 4; ++nt) {
        f32x4 y = acc[rg][nt] * rs - u4[nt] * rm + v4[nt];
        u32 w0 = f2bf2(gelu_f(y[0]), gelu_f(y[1]));
        u32 w1 = f2bf2(gelu_f(y[2]), gelu_f(y[3]));
        int slot = wc * 8 + nt * 2 + (hi >> 1);
        *(u32x2*)(xLDS + r * 512 + ((slot ^ (r & 7)) << 4) + (hi & 1) * 8) = u32x2{w0, w1};
      }
    }
  }
  __syncthreads();            // g ready

  // ---- GEMM3: acc = g x W_ff2 (K=256) ----
#pragma unroll
  for (int rg = 0; rg < 4; ++rg)
#pragma unroll
    for (int nt = 0; nt < 4; ++nt) acc[rg][nt] = f32x4{0.f, 0.f, 0.f, 0.f};
  run_gemm<8, 512>(acc, xLDS, W2t, lo, hi, wc);

  // ---- EPI3: +b_ff2 + residual(eh regs); edge LN stats ----
  {
    f32x4 b2[4];
#pragma unroll
    for (int nt = 0; nt < 4; ++nt)
      b2[nt] = *(const f32x4*)(b_ff2 + wc * 64 + nt * 16 + hi * 4);
#pragma unroll
    for (int rg = 0; rg < 4; ++rg) {
      int r = rg * 16 + lo;
      float ss = 0.f, qq = 0.f;
#pragma unroll
      for (int nt = 0; nt < 4; ++nt) {
        f32x4 x = acc[rg][nt] + b2[nt];
        x[0] += bf2f((u16)(ehreg[rg][nt][0] & 0xffffu));
        x[1] += bf2f((u16)(ehreg[rg][nt][0] >> 16));
        x[2] += bf2f((u16)(ehreg[rg][nt][1] & 0xffffu));
        x[3] += bf2f((u16)(ehreg[rg][nt][1] >> 16));
        acc[rg][nt] = x;
        ss += x[0] + x[1] + x[2] + x[3];
        qq += x[0]*x[0] + x[1]*x[1] + x[2]*x[2] + x[3]*x[3];
      }
      ss += __shfl_xor(ss, 16); ss += __shfl_xor(ss, 32);
      qq += __shfl_xor(qq, 16); qq += __shfl_xor(qq, 32);
      if (hi == 0) { part[wc][r][0] = ss; part[wc][r][1] = qq; }
    }
  }
  __syncthreads();            // GEMM3 reads done; part complete
  if (tid < 64) {
    float ss = part[0][tid][0] + part[1][tid][0] + part[2][tid][0] + part[3][tid][0];
    float qq = part[0][tid][1] + part[1][tid][1] + part[2][tid][1] + part[3][tid][1];
    float m  = ss * (1.f / 256.f);
    float var = qq * (1.f / 256.f) - m * m;
    part[0][tid][0] = m;
    part[0][tid][1] = rsqrtf(var + 1e-5f);
  }
  __syncthreads();

  // ---- edge_out (LN, fp32) + eo bf16 -> xLDS ----
  {
    f32x4 ge4[4], be4[4];
#pragma unroll
    for (int nt = 0; nt < 4; ++nt) {
      ge4[nt] = *(const f32x4*)(g_edge + wc * 64 + nt * 16 + hi * 4);
      be4[nt] = *(const f32x4*)(b_edge + wc * 64 + nt * 16 + hi * 4);
    }
#pragma unroll
    for (int rg = 0; rg < 4; ++rg) {
      int r = rg * 16 + lo;
      float m2  = part[0][r][0];
      float rs2 = part[0][r][1];
#pragma unroll
      for (int nt = 0; nt < 4; ++nt) {
        f32x4 x = acc[rg][nt];
        u32 w0 = f2bf2(x[0], x[1]);
        u32 w1 = f2bf2(x[2], x[3]);
        int slot = wc * 8 + nt * 2 + (hi >> 1);
        *(u32x2*)(xLDS + r * 512 + ((slot ^ (r & 7)) << 4) + (hi & 1) * 8) = u32x2{w0, w1};
        f32x4 o = (x - m2) * rs2 * ge4[nt] + be4[nt];
        *(f32x4*)(edge_out + (size_t)(tile0 + r) * 256 + wc * 64 + nt * 16 + hi * 4) = o;
      }
    }
  }
  __syncthreads();            // eo ready

  // ---- node aggregation (2 nodes) + node LN ----
  {
    int nd = tid >> 7;                 // node within block (wave-uniform)
    int c0 = (tid & 127) * 2;          // column pair
    int chunk = c0 >> 3;
    int wib = (c0 & 7) * 2;            // byte within 16B chunk
    float s0 = 0.f, s1 = 0.f;
#pragma unroll
    for (int r32 = 0; r32 < 32; ++r32) {
      int r = nd * 32 + r32;
      if (lm[r] != 0) {
        u32 w = *(const u32*)(xLDS + r * 512 + ((chunk ^ (r & 7)) << 4) + wib);
        s0 += bf2f((u16)(w & 0xffffu));
        s1 += bf2f((u16)(w >> 16));
      }
    }
    float ss = s0 + s1, qq = s0 * s0 + s1 * s1;
#pragma unroll
    for (int d = 1; d < 64; d <<= 1) { ss += __shfl_xor(ss, d); qq += __shfl_xor(qq, d); }
    if (lane == 0) { red[wc][0] = ss; red[wc][1] = qq; }
    __syncthreads();
    ss = red[nd * 2][0] + red[nd * 2 + 1][0];
    qq = red[nd * 2][1] + red[nd * 2 + 1][1];
    float m   = ss * (1.f / 256.f);
    float var = qq * (1.f / 256.f) - m * m;
    float rs  = rsqrtf(var + 1e-5f);
    f32x2 gn = *(const f32x2*)(g_node + c0);
    f32x2 bn = *(const f32x2*)(b_node + c0);
    f32x2 o;
    o[0] = (s0 - m) * rs * gn[0] + bn[0];
    o[1] = (s1 - m) * rs * gn[1] + bn[1];
    *(f32x2*)(node_out + (size_t)(blockIdx.x * 2 + nd) * 256 + c0) = o;
  }
}

extern "C" void kernel_launch(void* const* d_in, const int* in_sizes, int n_in,
                              void* d_out, int out_size, void* d_ws, size_t ws_size,
                              hipStream_t stream)
{
  (void)in_sizes; (void)n_in; (void)out_size; (void)ws_size;
  const float* edge_features = (const float*)d_in[0];
  const int*   nmask  = (const int*)d_in[1];
  const float* W_lin  = (const float*)d_in[2];
  const float* b_lin  = (const float*)d_in[3];
  const float* g_pre  = (const float*)d_in[4];
  const float* b_pre  = (const float*)d_in[5];
  const float* W_ff1  = (const float*)d_in[6];
  const float* b_ff1  = (const float*)d_in[7];
  const float* W_ff2  = (const float*)d_in[8];
  const float* b_ff2  = (const float*)d_in[9];
  const float* g_node = (const float*)d_in[10];
  const float* b_node = (const float*)d_in[11];
  const float* g_edge = (const float*)d_in[12];
  const float* b_edge = (const float*)d_in[13];

  char* ws = (char*)d_ws;
  u16* Wlt   = (u16*)ws;   ws += 256 * 128 * 2;
  u16* W1gt  = (u16*)ws;   ws += 256 * 256 * 2;
  u16* W2t   = (u16*)ws;   ws += 256 * 256 * 2;
  float* ucp = (float*)ws; ws += 256 * 4;
  float* vcp = (float*)ws; ws += 256 * 4;

  float* node_out = (float*)d_out;
  float* edge_out = (float*)d_out + (size_t)NNODE * HD;

  prep_weights<<<640, 256, 0, stream>>>(W_lin, g_pre, W_ff1, W_ff2, Wlt, W1gt, W2t);
  prep_uv<<<256, 64, 0, stream>>>(W_ff1, g_pre, b_pre, b_ff1, ucp, vcp);
  mega_kernel<<<5000, 256, 0, stream>>>(edge_features, nmask, Wlt, W1gt, W2t,
                                        b_lin, ucp, vcp, b_ff2, g_edge, b_edge,
                                        g_node, b_node, node_out, edge_out);
}

// Round 7
// 699.447 us; speedup vs baseline: 1.0860x; 1.0427x over previous
//
#include <hip/hip_runtime.h>
#include <hip/hip_bf16.h>

typedef float f32x4 __attribute__((ext_vector_type(4)));
typedef float f32x2 __attribute__((ext_vector_type(2)));
typedef short bf16x8 __attribute__((ext_vector_type(8)));
typedef unsigned int u32;
typedef unsigned int u32x2 __attribute__((ext_vector_type(2)));
typedef unsigned short u16;

#define DEVI static __device__ __forceinline__

static constexpr int HD    = 256;      // hidden
static constexpr int NNODE = 10000;

DEVI u16 f2bf(float f) {
  __hip_bfloat16 h = __float2bfloat16(f);   // RNE; pairs fuse into v_cvt_pk_bf16_f32
  return __builtin_bit_cast(u16, h);
}
DEVI u32 f2bf2(float a, float b) {          // pack two bf16 into u32 (low = a)
  return (u32)f2bf(a) | ((u32)f2bf(b) << 16);
}
DEVI float bf2f(u16 s) {
  u32 u = ((u32)s) << 16;
  return __builtin_bit_cast(float, u);
}
DEVI float gelu_f(float y) {
  float z = 0.7978845608028654f * (y + 0.044715f * y * y * y);
  float E = __expf(2.f * z);
  return y * (1.f - 1.f / (E + 1.f));
}

// ---------------- weight prep ----------------
// Wlt [256][128] = W_lin^T (bf16); W1gt[256][256] = (g_pre*W_ff1)^T; W2t = W_ff2^T
__global__ void prep_weights(const float* __restrict__ W_lin, const float* __restrict__ g_pre,
                             const float* __restrict__ W_ff1, const float* __restrict__ W_ff2,
                             u16* __restrict__ Wlt, u16* __restrict__ W1gt, u16* __restrict__ W2t)
{
  int e = blockIdx.x * 256 + threadIdx.x;
  if (e < 32768) {
    int c = e >> 7, k = e & 127;
    Wlt[e] = f2bf(W_lin[k * 256 + c]);
  } else if (e < 32768 + 65536) {
    int e2 = e - 32768; int c = e2 >> 8, k = e2 & 255;
    W1gt[e2] = f2bf(g_pre[k] * W_ff1[k * 256 + c]);
  } else if (e < 163840) {
    int e3 = e - 98304; int c = e3 >> 8, k = e3 & 255;
    W2t[e3] = f2bf(W_ff2[k * 256 + c]);
  }
}

// 256 blocks x 64 lanes: block c computes u[c], v[c]
__global__ void prep_uv(const float* __restrict__ W_ff1, const float* __restrict__ g_pre,
                        const float* __restrict__ b_pre, const float* __restrict__ b_ff1,
                        float* __restrict__ u, float* __restrict__ v)
{
  int c = blockIdx.x;
  int lane = threadIdx.x;
  float uu = 0.f, vv = 0.f;
#pragma unroll
  for (int i = 0; i < 4; ++i) {
    int k = lane + i * 64;
    float w = W_ff1[k * 256 + c];
    uu += g_pre[k] * w;
    vv += b_pre[k] * w;
  }
#pragma unroll
  for (int d = 1; d < 64; d <<= 1) { uu += __shfl_xor(uu, d); vv += __shfl_xor(vv, d); }
  if (lane == 0) {
    u[c] = uu;
    v[c] = vv + b_ff1[c];
  }
}

// ---------------- GEMM inner loop (no barriers, 1-step B prefetch) ----------------
// A from swizzled xLDS (STRIDE bytes/row, 16B chunk index ^ (r&7));
// B direct from global W^T (L2-resident); per-nt base pointer + imm offset ks*64.
// acc layout: row r = rg*16 + lo; col = wc*64 + nt*16 + hi*4 + j.
template<int NK, int STRIDE>
DEVI void run_gemm(f32x4 (&acc)[4][4], const char* __restrict__ xbase,
                   const u16* __restrict__ Wt, int lo, int hi, int wc)
{
  const char* bp[4];
#pragma unroll
  for (int nt = 0; nt < 4; ++nt) {
    int cc = wc * 64 + nt * 16 + lo;
    bp[nt] = (const char*)Wt + (size_t)cc * (NK * 64) + hi * 16;
  }
  bf16x8 bcur[4];
#pragma unroll
  for (int nt = 0; nt < 4; ++nt) bcur[nt] = *(const bf16x8*)(bp[nt]);
#pragma unroll
  for (int ks = 0; ks < NK; ++ks) {
    bf16x8 bnxt[4];
    if (ks + 1 < NK) {
#pragma unroll
      for (int nt = 0; nt < 4; ++nt) bnxt[nt] = *(const bf16x8*)(bp[nt] + (ks + 1) * 64);
    }
    bf16x8 a[4];
#pragma unroll
    for (int rg = 0; rg < 4; ++rg) {
      int r = rg * 16 + lo;
      a[rg] = *(const bf16x8*)(xbase + r * STRIDE + (((ks * 4 + hi) ^ (r & 7)) << 4));
    }
#pragma unroll
    for (int nt = 0; nt < 4; ++nt)
#pragma unroll
      for (int rg = 0; rg < 4; ++rg)
        acc[rg][nt] = __builtin_amdgcn_mfma_f32_16x16x32_bf16(bcur[nt], a[rg], acc[rg][nt], 0, 0, 0);
    if (ks + 1 < NK) {
#pragma unroll
      for (int nt = 0; nt < 4; ++nt) bcur[nt] = bnxt[nt];
    }
  }
}

// ---------------- fused megakernel ----------------
// Block = 64 rows = 2 nodes. 256 threads = 4 waves (1 row-group x 4 col-groups).
// xLDS [64][256] bf16 (chunk-swizzled) serves as: A-stage (16KB) -> eh -> g -> eo.
// Residual eh kept packed-bf16 in 32 registers.
// edge_out stores are LANE-LINEAR full 1KB rows (no partial-line HBM writes).
__global__ __launch_bounds__(256, 3)
void mega_kernel(const float* __restrict__ EF, const int* __restrict__ nmask,
                 const u16* __restrict__ Wlt, const u16* __restrict__ W1gt, const u16* __restrict__ W2t,
                 const float* __restrict__ b_lin, const float* __restrict__ uc, const float* __restrict__ vc,
                 const float* __restrict__ b_ff2, const float* __restrict__ g_edge, const float* __restrict__ b_edge,
                 const float* __restrict__ g_node, const float* __restrict__ b_node,
                 float* __restrict__ node_out, float* __restrict__ edge_out)
{
  const int tid  = threadIdx.x;
  const int lane = tid & 63;
  const int wc   = tid >> 6;      // wave = column group 0..3
  const int lo   = lane & 15;
  const int hi   = lane >> 4;
  const int tile0 = blockIdx.x * 64;

  __shared__ char  xLDS[32768];
  __shared__ float part[4][64][2];
  __shared__ int   lm[64];
  __shared__ float red[4][2];

  if (tid < 64) lm[tid] = nmask[tile0 + tid];

  // ---- stage A: EF fp32 -> bf16 into xLDS rows of 256B (swizzled 16B chunks) ----
#pragma unroll
  for (int it = 0; it < 4; ++it) {
    int idx = it * 256 + tid;
    int r = idx >> 4, sl = idx & 15;
    const float* src = EF + (size_t)(tile0 + r) * 128 + sl * 8;
    f32x4 x0 = *(const f32x4*)src;
    f32x4 x1 = *(const f32x4*)(src + 4);
    bf16x8 t;
    u32 p0 = f2bf2(x0[0], x0[1]);
    u32 p1 = f2bf2(x0[2], x0[3]);
    u32 p2 = f2bf2(x1[0], x1[1]);
    u32 p3 = f2bf2(x1[2], x1[3]);
    t[0] = (short)(p0 & 0xffffu); t[1] = (short)(p0 >> 16);
    t[2] = (short)(p1 & 0xffffu); t[3] = (short)(p1 >> 16);
    t[4] = (short)(p2 & 0xffffu); t[5] = (short)(p2 >> 16);
    t[6] = (short)(p3 & 0xffffu); t[7] = (short)(p3 >> 16);
    *(bf16x8*)(xLDS + r * 256 + ((sl ^ (r & 7)) << 4)) = t;
  }
  __syncthreads();

  f32x4 acc[4][4];
#pragma unroll
  for (int rg = 0; rg < 4; ++rg)
#pragma unroll
    for (int nt = 0; nt < 4; ++nt) acc[rg][nt] = f32x4{0.f, 0.f, 0.f, 0.f};

  // ---- GEMM1: eh = EF x W_lin (K=128) ----
  run_gemm<4, 256>(acc, xLDS, Wlt, lo, hi, wc);

  // ---- EPI1: +b_lin, keep eh packed in regs, row stats ----
  u32x2 ehreg[4][4];
  {
    f32x4 bl[4];
#pragma unroll
    for (int nt = 0; nt < 4; ++nt)
      bl[nt] = *(const f32x4*)(b_lin + wc * 64 + nt * 16 + hi * 4);
#pragma unroll
    for (int rg = 0; rg < 4; ++rg) {
      int r = rg * 16 + lo;
      float ss = 0.f, qq = 0.f;
#pragma unroll
      for (int nt = 0; nt < 4; ++nt) {
        f32x4 x = acc[rg][nt] + bl[nt];
        ehreg[rg][nt] = u32x2{f2bf2(x[0], x[1]), f2bf2(x[2], x[3])};
        ss += x[0] + x[1] + x[2] + x[3];
        qq += x[0]*x[0] + x[1]*x[1] + x[2]*x[2] + x[3]*x[3];
      }
      ss += __shfl_xor(ss, 16); ss += __shfl_xor(ss, 32);
      qq += __shfl_xor(qq, 16); qq += __shfl_xor(qq, 32);
      if (hi == 0) { part[wc][r][0] = ss; part[wc][r][1] = qq; }
    }
  }
  __syncthreads();            // GEMM1 A-reads done; part complete
  if (tid < 64) {
    float ss = part[0][tid][0] + part[1][tid][0] + part[2][tid][0] + part[3][tid][0];
    float qq = part[0][tid][1] + part[1][tid][1] + part[2][tid][1] + part[3][tid][1];
    float m  = ss * (1.f / 256.f);
    float var = qq * (1.f / 256.f) - m * m;
    part[0][tid][0] = m;
    part[0][tid][1] = rsqrtf(var + 1e-5f);
  }
  // write eh bf16 into xLDS (rows now 512B): slot sl holds cols sl*8..+8, ^ (r&7)
#pragma unroll
  for (int rg = 0; rg < 4; ++rg) {
    int r = rg * 16 + lo;
#pragma unroll
    for (int nt = 0; nt < 4; ++nt) {
      int slot = wc * 8 + nt * 2 + (hi >> 1);
      *(u32x2*)(xLDS + r * 512 + ((slot ^ (r & 7)) << 4) + (hi & 1) * 8) = ehreg[rg][nt];
    }
  }
  __syncthreads();            // eh + stats ready

  // ---- GEMM2: acc = eh x (g_pre*W_ff1) (K=256) ----
#pragma unroll
  for (int rg = 0; rg < 4; ++rg)
#pragma unroll
    for (int nt = 0; nt < 4; ++nt) acc[rg][nt] = f32x4{0.f, 0.f, 0.f, 0.f};
  run_gemm<8, 512>(acc, xLDS, W1gt, lo, hi, wc);
  __syncthreads();            // all eh reads done before overwrite with g

  // ---- EPI2: folded pre-LN + gelu -> g into xLDS ----
  {
    f32x4 u4[4], v4[4];
#pragma unroll
    for (int nt = 0; nt < 4; ++nt) {
      u4[nt] = *(const f32x4*)(uc + wc * 64 + nt * 16 + hi * 4);
      v4[nt] = *(const f32x4*)(vc + wc * 64 + nt * 16 + hi * 4);
    }
#pragma unroll
    for (int rg = 0; rg < 4; ++rg) {
      int r = rg * 16 + lo;
      float m  = part[0][r][0];
      float rs = part[0][r][1];
      float rm = m * rs;
#pragma unroll
      for (int nt = 0; nt < 4; ++nt) {
        f32x4 y = acc[rg][nt] * rs - u4[nt] * rm + v4[nt];
        u32 w0 = f2bf2(gelu_f(y[0]), gelu_f(y[1]));
        u32 w1 = f2bf2(gelu_f(y[2]), gelu_f(y[3]));
        int slot = wc * 8 + nt * 2 + (hi >> 1);
        *(u32x2*)(xLDS + r * 512 + ((slot ^ (r & 7)) << 4) + (hi & 1) * 8) = u32x2{w0, w1};
      }
    }
  }
  __syncthreads();            // g ready

  // ---- GEMM3: acc = g x W_ff2 (K=256) ----
#pragma unroll
  for (int rg = 0; rg < 4; ++rg)
#pragma unroll
    for (int nt = 0; nt < 4; ++nt) acc[rg][nt] = f32x4{0.f, 0.f, 0.f, 0.f};
  run_gemm<8, 512>(acc, xLDS, W2t, lo, hi, wc);

  // ---- EPI3: +b_ff2 + residual(eh regs); edge LN stats ----
  {
    f32x4 b2[4];
#pragma unroll
    for (int nt = 0; nt < 4; ++nt)
      b2[nt] = *(const f32x4*)(b_ff2 + wc * 64 + nt * 16 + hi * 4);
#pragma unroll
    for (int rg = 0; rg < 4; ++rg) {
      int r = rg * 16 + lo;
      float ss = 0.f, qq = 0.f;
#pragma unroll
      for (int nt = 0; nt < 4; ++nt) {
        f32x4 x = acc[rg][nt] + b2[nt];
        x[0] += bf2f((u16)(ehreg[rg][nt][0] & 0xffffu));
        x[1] += bf2f((u16)(ehreg[rg][nt][0] >> 16));
        x[2] += bf2f((u16)(ehreg[rg][nt][1] & 0xffffu));
        x[3] += bf2f((u16)(ehreg[rg][nt][1] >> 16));
        acc[rg][nt] = x;
        ss += x[0] + x[1] + x[2] + x[3];
        qq += x[0]*x[0] + x[1]*x[1] + x[2]*x[2] + x[3]*x[3];
      }
      ss += __shfl_xor(ss, 16); ss += __shfl_xor(ss, 32);
      qq += __shfl_xor(qq, 16); qq += __shfl_xor(qq, 32);
      if (hi == 0) { part[wc][r][0] = ss; part[wc][r][1] = qq; }
    }
  }
  __syncthreads();            // GEMM3 reads done; part complete
  if (tid < 64) {
    float ss = part[0][tid][0] + part[1][tid][0] + part[2][tid][0] + part[3][tid][0];
    float qq = part[0][tid][1] + part[1][tid][1] + part[2][tid][1] + part[3][tid][1];
    float m  = ss * (1.f / 256.f);
    float var = qq * (1.f / 256.f) - m * m;
    part[0][tid][0] = m;
    part[0][tid][1] = rsqrtf(var + 1e-5f);
  }
  __syncthreads();

  // ---- (A) eo bf16 -> xLDS (GEMM fragment layout) ----
#pragma unroll
  for (int rg = 0; rg < 4; ++rg) {
    int r = rg * 16 + lo;
#pragma unroll
    for (int nt = 0; nt < 4; ++nt) {
      f32x4 x = acc[rg][nt];
      int slot = wc * 8 + nt * 2 + (hi >> 1);
      *(u32x2*)(xLDS + r * 512 + ((slot ^ (r & 7)) << 4) + (hi & 1) * 8) =
          u32x2{f2bf2(x[0], x[1]), f2bf2(x[2], x[3])};
    }
  }
  __syncthreads();            // eo ready in xLDS

  // ---- (B) edge_out: lane-linear full-row stores (1KB contiguous per instr) ----
  {
    f32x4 ge4 = *(const f32x4*)(g_edge + lane * 4);
    f32x4 be4 = *(const f32x4*)(b_edge + lane * 4);
    int chunk = lane >> 1;
    int half  = (lane & 1) * 8;
#pragma unroll
    for (int rr = 0; rr < 16; ++rr) {
      int r = wc * 16 + rr;
      float m2  = part[0][r][0];
      float rs2 = part[0][r][1];
      u32x2 w = *(const u32x2*)(xLDS + r * 512 + ((chunk ^ (r & 7)) << 4) + half);
      f32x4 x;
      x[0] = bf2f((u16)(w[0] & 0xffffu));
      x[1] = bf2f((u16)(w[0] >> 16));
      x[2] = bf2f((u16)(w[1] & 0xffffu));
      x[3] = bf2f((u16)(w[1] >> 16));
      f32x4 o = (x - m2) * rs2 * ge4 + be4;
      *(f32x4*)(edge_out + (size_t)(tile0 + r) * 256 + lane * 4) = o;
    }
  }

  // ---- node aggregation (2 nodes) + node LN ----
  {
    int nd = tid >> 7;                 // node within block (wave-uniform)
    int c0 = (tid & 127) * 2;          // column pair
    int chunk = c0 >> 3;
    int wib = (c0 & 7) * 2;            // byte within 16B chunk
    float s0 = 0.f, s1 = 0.f;
#pragma unroll
    for (int r32 = 0; r32 < 32; ++r32) {
      int r = nd * 32 + r32;
      if (lm[r] != 0) {
        u32 w = *(const u32*)(xLDS + r * 512 + ((chunk ^ (r & 7)) << 4) + wib);
        s0 += bf2f((u16)(w & 0xffffu));
        s1 += bf2f((u16)(w >> 16));
      }
    }
    float ss = s0 + s1, qq = s0 * s0 + s1 * s1;
#pragma unroll
    for (int d = 1; d < 64; d <<= 1) { ss += __shfl_xor(ss, d); qq += __shfl_xor(qq, d); }
    if (lane == 0) { red[wc][0] = ss; red[wc][1] = qq; }
    __syncthreads();
    ss = red[nd * 2][0] + red[nd * 2 + 1][0];
    qq = red[nd * 2][1] + red[nd * 2 + 1][1];
    float m   = ss * (1.f / 256.f);
    float var = qq * (1.f / 256.f) - m * m;
    float rs  = rsqrtf(var + 1e-5f);
    f32x2 gn = *(const f32x2*)(g_node + c0);
    f32x2 bn = *(const f32x2*)(b_node + c0);
    f32x2 o;
    o[0] = (s0 - m) * rs * gn[0] + bn[0];
    o[1] = (s1 - m) * rs * gn[1] + bn[1];
    *(f32x2*)(node_out + (size_t)(blockIdx.x * 2 + nd) * 256 + c0) = o;
  }
}

extern "C" void kernel_launch(void* const* d_in, const int* in_sizes, int n_in,
                              void* d_out, int out_size, void* d_ws, size_t ws_size,
                              hipStream_t stream)
{
  (void)in_sizes; (void)n_in; (void)out_size; (void)ws_size;
  const float* edge_features = (const float*)d_in[0];
  const int*   nmask  = (const int*)d_in[1];
  const float* W_lin  = (const float*)d_in[2];
  const float* b_lin  = (const float*)d_in[3];
  const float* g_pre  = (const float*)d_in[4];
  const float* b_pre  = (const float*)d_in[5];
  const float* W_ff1  = (const float*)d_in[6];
  const float* b_ff1  = (const float*)d_in[7];
  const float* W_ff2  = (const float*)d_in[8];
  const float* b_ff2  = (const float*)d_in[9];
  const float* g_node = (const float*)d_in[10];
  const float* b_node = (const float*)d_in[11];
  const float* g_edge = (const float*)d_in[12];
  const float* b_edge = (const float*)d_in[13];

  char* ws = (char*)d_ws;
  u16* Wlt   = (u16*)ws;   ws += 256 * 128 * 2;
  u16* W1gt  = (u16*)ws;   ws += 256 * 256 * 2;
  u16* W2t   = (u16*)ws;   ws += 256 * 256 * 2;
  float* ucp = (float*)ws; ws += 256 * 4;
  float* vcp = (float*)ws; ws += 256 * 4;

  float* node_out = (float*)d_out;
  float* edge_out = (float*)d_out + (size_t)NNODE * HD;

  prep_weights<<<640, 256, 0, stream>>>(W_lin, g_pre, W_ff1, W_ff2, Wlt, W1gt, W2t);
  prep_uv<<<256, 64, 0, stream>>>(W_ff1, g_pre, b_pre, b_ff1, ucp, vcp);
  mega_kernel<<<5000, 256, 0, stream>>>(edge_features, nmask, Wlt, W1gt, W2t,
                                        b_lin, ucp, vcp, b_ff2, g_edge, b_edge,
                                        g_node, b_node, node_out, edge_out);
}